// Round 1
// baseline (301.139 us; speedup 1.0000x reference)
//
#include <hip/hip_runtime.h>
#include <stdint.h>

// Problem constants
#define DM   768
#define NH   12
#define DH   64
#define SEQ  2048
#define BATCH 4
#define LDQKV 2304   // 3*DM

using bf16x8 = __attribute__((ext_vector_type(8))) short;
using f32x4  = __attribute__((ext_vector_type(4))) float;

__device__ __forceinline__ unsigned short f2bf(float f) {
  union { float f; unsigned int u; } v; v.f = f;
  unsigned int u = v.u;
  u += 0x7fffu + ((u >> 16) & 1u);           // RNE to bf16
  return (unsigned short)(u >> 16);
}

__device__ __forceinline__ void gload_lds16(const unsigned short* g, unsigned short* l) {
  __builtin_amdgcn_global_load_lds(
      (__attribute__((address_space(1))) void*)g,
      (__attribute__((address_space(3))) void*)l, 16, 0, 0);
}

// ---------------------------------------------------------------- pack_x
// x fp32 [8192*768] -> bf16
__global__ void pack_x(const float* __restrict__ x, unsigned short* __restrict__ xb) {
  int i = (blockIdx.x * 256 + threadIdx.x) * 4;
  float4 v = *(const float4*)(x + i);
  ushort4 o;
  o.x = f2bf(v.x); o.y = f2bf(v.y); o.z = f2bf(v.z); o.w = f2bf(v.w);
  *(ushort4*)(xb + i) = o;
}

// ---------------------------------------------------------------- pack_w
// wqkv_t[j][d] = W_{q|k|v}[n,d,h] (j = which*768 + n*64 + h), W_Q scaled by 0.125
// wo_t[dcol][j] = W_O[n,h,dcol]  (j = n*64+h)
// biasq[j] = (0.125*bQ | bK | bV)
__global__ void pack_w(const float* __restrict__ Wq, const float* __restrict__ Wk,
                       const float* __restrict__ Wv, const float* __restrict__ Wo,
                       const float* __restrict__ bQ, const float* __restrict__ bK,
                       const float* __restrict__ bV,
                       unsigned short* __restrict__ wqkv_t,
                       unsigned short* __restrict__ wo_t,
                       float* __restrict__ biasq) {
  int idx = blockIdx.x * 256 + threadIdx.x;
  const int NW = 2304 * 768;
  const int NO = 768 * 768;
  if (idx < NW) {
    int j = idx / 768, d = idx - j * 768;
    int which = j / 768, nh = j - which * 768;
    const float* W = (which == 0) ? Wq : ((which == 1) ? Wk : Wv);
    float v = W[(nh >> 6) * (768 * 64) + d * 64 + (nh & 63)];
    if (which == 0) v *= 0.125f;
    wqkv_t[idx] = f2bf(v);
  } else if (idx < NW + NO) {
    int k = idx - NW;
    int dcol = k / 768, j = k - dcol * 768;
    wo_t[k] = f2bf(Wo[j * 768 + dcol]);
  } else if (idx < NW + NO + 2304) {
    int j = idx - (NW + NO);
    int which = j / 768, nh = j - which * 768;
    float bv = (which == 0) ? 0.125f * bQ[nh] : ((which == 1) ? bK[nh] : bV[nh]);
    biasq[j] = bv;
  }
}

// ---------------------------------------------------------------- gemm_bt
// C[M][N] = A[M][K] * Bt[N][K]^T + bias[N].  128x128 tile, BK=64, 4 waves.
// LDS tiles [128][64] bf16, staged via global_load_lds w/ source-swizzled cols,
// read with matching XOR swizzle (slot ^= row&7, 16B slots).
template<bool F32OUT>
__global__ __launch_bounds__(256)
void gemm_bt(const unsigned short* __restrict__ A, const unsigned short* __restrict__ Bt,
             const float* __restrict__ bias, void* __restrict__ Cout,
             int M, int N, int K) {
  __shared__ __align__(16) unsigned short As[128 * 64];
  __shared__ __align__(16) unsigned short Bs[128 * 64];
  const int tid = threadIdx.x;
  const int lane = tid & 63, wid = tid >> 6;
  const int l15 = lane & 15, g = lane >> 4;
  const int wr = wid >> 1, wc = wid & 1;
  const int m0 = blockIdx.y * 128, n0 = blockIdx.x * 128;

  // staging: thread t, pass p loads 16B: row = p*32 + t/8, lds slot = t&7,
  // source col block = (slot ^ (row&7)) (pass-invariant since 32%8==0)
  const int srow = tid >> 3, sslot = tid & 7;
  const int scol = ((sslot ^ (srow & 7)) << 3);
  const unsigned short* ag = A  + (size_t)(m0 + srow) * K + scol;
  const unsigned short* bg = Bt + (size_t)(n0 + srow) * K + scol;

  f32x4 acc[4][4];
  const f32x4 zz = {0.f, 0.f, 0.f, 0.f};
#pragma unroll
  for (int i = 0; i < 4; ++i)
#pragma unroll
    for (int j = 0; j < 4; ++j) acc[i][j] = zz;

  for (int kt = 0; kt < K; kt += 64) {
#pragma unroll
    for (int p = 0; p < 4; ++p) {
      gload_lds16(ag + (size_t)p * 32 * K + kt, As + p * 2048 + wid * 512);
      gload_lds16(bg + (size_t)p * 32 * K + kt, Bs + p * 2048 + wid * 512);
    }
    __syncthreads();
    bf16x8 af[2][4], bf[2][4];
#pragma unroll
    for (int mf = 0; mf < 4; ++mf) {
      int ra = wr * 64 + mf * 16 + l15;
      int rb = wc * 64 + mf * 16 + l15;
      af[0][mf] = *(const bf16x8*)&As[ra * 64 + (((0 + g) ^ (ra & 7)) << 3)];
      af[1][mf] = *(const bf16x8*)&As[ra * 64 + (((4 + g) ^ (ra & 7)) << 3)];
      bf[0][mf] = *(const bf16x8*)&Bs[rb * 64 + (((0 + g) ^ (rb & 7)) << 3)];
      bf[1][mf] = *(const bf16x8*)&Bs[rb * 64 + (((4 + g) ^ (rb & 7)) << 3)];
    }
#pragma unroll
    for (int ks = 0; ks < 2; ++ks)
#pragma unroll
      for (int mf = 0; mf < 4; ++mf)
#pragma unroll
        for (int nf = 0; nf < 4; ++nf)
          acc[mf][nf] = __builtin_amdgcn_mfma_f32_16x16x32_bf16(
              af[ks][mf], bf[ks][nf], acc[mf][nf], 0, 0, 0);
    __syncthreads();
  }

#pragma unroll
  for (int nf = 0; nf < 4; ++nf) {
    int col = n0 + wc * 64 + nf * 16 + l15;
    float bv = bias[col];
#pragma unroll
    for (int mf = 0; mf < 4; ++mf) {
      int row = m0 + wr * 64 + mf * 16 + g * 4;
#pragma unroll
      for (int i = 0; i < 4; ++i) {
        float v = acc[mf][nf][i] + bv;
        if constexpr (F32OUT)
          ((float*)Cout)[(size_t)(row + i) * N + col] = v;
        else
          ((unsigned short*)Cout)[(size_t)(row + i) * N + col] = f2bf(v);
      }
    }
  }
}

// ---------------------------------------------------------------- attn_fwd
// Flash attention, causal. Grid (16 qtiles, 12 heads, 4 batch), 256 threads.
// Q tile 128 rows (32/wave, in regs); KV tiles of 64.
// qkv layout: [b*2048+s][2304], Q at col n*64, K at 768+n*64, V at 1536+n*64.
// Z out: bf16 [8192][768], col = n*64+d.
__global__ __launch_bounds__(256)
void attn_fwd(const unsigned short* __restrict__ qkv, unsigned short* __restrict__ Z) {
  __shared__ __align__(16) unsigned short Kl[64 * 64];
  __shared__ __align__(16) unsigned short Vt[64 * 64];   // [d][key], swizzled
  __shared__ __align__(16) unsigned short Pl[4 * 32 * 64]; // per-wave [32 q][64 key], swizzled

  const int tid = threadIdx.x;
  const int lane = tid & 63, wid = tid >> 6;
  const int l15 = lane & 15, g = lane >> 4;
  const int qt = blockIdx.x, head = blockIdx.y, b = blockIdx.z;
  const int q0 = qt * 128;
  const size_t rowbase = (size_t)b * SEQ;

  // Q fragments in registers (scale 0.125 already folded into W_Q)
  bf16x8 qf[2][2]; // [ks][mf]
#pragma unroll
  for (int mf = 0; mf < 2; ++mf) {
    const unsigned short* qrow =
        qkv + (rowbase + q0 + wid * 32 + mf * 16 + l15) * LDQKV + head * 64;
    qf[0][mf] = *(const bf16x8*)(qrow + 0  + g * 8);
    qf[1][mf] = *(const bf16x8*)(qrow + 32 + g * 8);
  }

  f32x4 o[2][4];
  const f32x4 zz = {0.f, 0.f, 0.f, 0.f};
#pragma unroll
  for (int mf = 0; mf < 2; ++mf)
#pragma unroll
    for (int df = 0; df < 4; ++df) o[mf][df] = zz;
  float mst[2][4], lst[2][4];
#pragma unroll
  for (int mf = 0; mf < 2; ++mf)
#pragma unroll
    for (int i = 0; i < 4; ++i) { mst[mf][i] = -1e30f; lst[mf][i] = 0.f; }

  // K staging (global_load_lds, source-swizzled)
  const int srow = tid >> 3, sslot = tid & 7;
  const int scol = ((sslot ^ (srow & 7)) << 3);
  const unsigned short* kg_ = qkv + (rowbase + srow) * LDQKV + 768 + head * 64 + scol;

  // V micro-transpose mapping: thread handles keys vkg*4..+3, d cols vdg*4..+3
  const int vkg = tid & 15, vdg = tid >> 4;
  const unsigned short* vg_ = qkv + (rowbase + vkg * 4) * LDQKV + 1536 + head * 64 + vdg * 4;

  const int nt = 2 * qt + 2;
  for (int kt = 0; kt < nt; ++kt) {
    __syncthreads();
    // stage K: rows kt*64 .. +63, 2 passes of 32 rows
    gload_lds16(kg_ + (size_t)(kt * 64) * LDQKV,      Kl + wid * 512);
    gload_lds16(kg_ + (size_t)(kt * 64 + 32) * LDQKV, Kl + 2048 + wid * 512);
    // stage V transposed: Vt[d][key], 16B-slot swizzle (slot ^= d&7)
    ushort4 vv[4];
#pragma unroll
    for (int i = 0; i < 4; ++i)
      vv[i] = *(const ushort4*)(vg_ + (size_t)(kt * 64 + i) * LDQKV);
#pragma unroll
    for (int j = 0; j < 4; ++j) {
      int d = vdg * 4 + j;
      int swz = (vkg >> 1) ^ (d & 7);
      ushort4 w;
      w.x = ((const unsigned short*)&vv[0])[j];
      w.y = ((const unsigned short*)&vv[1])[j];
      w.z = ((const unsigned short*)&vv[2])[j];
      w.w = ((const unsigned short*)&vv[3])[j];
      *(ushort4*)&Vt[d * 64 + swz * 8 + (vkg & 1) * 4] = w;
    }
    __syncthreads();

    // ---- QK^T
    f32x4 s[2][4];
#pragma unroll
    for (int mf = 0; mf < 2; ++mf)
#pragma unroll
      for (int kf = 0; kf < 4; ++kf) s[mf][kf] = zz;
    bf16x8 kb[2][4];
#pragma unroll
    for (int kf = 0; kf < 4; ++kf) {
      int rk = kf * 16 + l15;
      kb[0][kf] = *(const bf16x8*)&Kl[rk * 64 + (((0 + g) ^ (rk & 7)) << 3)];
      kb[1][kf] = *(const bf16x8*)&Kl[rk * 64 + (((4 + g) ^ (rk & 7)) << 3)];
    }
#pragma unroll
    for (int ks = 0; ks < 2; ++ks)
#pragma unroll
      for (int mf = 0; mf < 2; ++mf)
#pragma unroll
        for (int kf = 0; kf < 4; ++kf)
          s[mf][kf] = __builtin_amdgcn_mfma_f32_16x16x32_bf16(
              qf[ks][mf], kb[ks][kf], s[mf][kf], 0, 0, 0);

    // causal mask on the last two tiles
    if (kt >= nt - 2) {
#pragma unroll
      for (int mf = 0; mf < 2; ++mf)
#pragma unroll
        for (int kf = 0; kf < 4; ++kf)
#pragma unroll
          for (int i = 0; i < 4; ++i) {
            int qg = q0 + wid * 32 + mf * 16 + 4 * g + i;
            int kg = kt * 64 + kf * 16 + l15;
            if (kg > qg) s[mf][kf][i] = -1e30f;
          }
    }

    // ---- online softmax (row = per (mf,i), cols spread over kf and 16 lanes)
#pragma unroll
    for (int mf = 0; mf < 2; ++mf)
#pragma unroll
      for (int i = 0; i < 4; ++i) {
        float mx = fmaxf(fmaxf(s[mf][0][i], s[mf][1][i]),
                         fmaxf(s[mf][2][i], s[mf][3][i]));
        mx = fmaxf(mx, __shfl_xor(mx, 1));
        mx = fmaxf(mx, __shfl_xor(mx, 2));
        mx = fmaxf(mx, __shfl_xor(mx, 4));
        mx = fmaxf(mx, __shfl_xor(mx, 8));
        float mnew = fmaxf(mst[mf][i], mx);
        float alpha = __expf(mst[mf][i] - mnew);
        mst[mf][i] = mnew;
        float rs = 0.f;
#pragma unroll
        for (int kf = 0; kf < 4; ++kf) {
          float p = __expf(s[mf][kf][i] - mnew);
          s[mf][kf][i] = p;
          rs += p;
        }
        rs += __shfl_xor(rs, 1);
        rs += __shfl_xor(rs, 2);
        rs += __shfl_xor(rs, 4);
        rs += __shfl_xor(rs, 8);
        lst[mf][i] = lst[mf][i] * alpha + rs;
#pragma unroll
        for (int df = 0; df < 4; ++df) o[mf][df][i] *= alpha;
      }

    // ---- write P to per-wave LDS [32 q][64 key], swizzled (slot ^= q&7)
#pragma unroll
    for (int mf = 0; mf < 2; ++mf)
#pragma unroll
      for (int kf = 0; kf < 4; ++kf)
#pragma unroll
        for (int i = 0; i < 4; ++i) {
          int ql = mf * 16 + 4 * g + i;
          int key = kf * 16 + l15;
          Pl[wid * 2048 + ql * 64 + ((((key >> 3) ^ (ql & 7)) << 3) | (key & 7))] =
              f2bf(s[mf][kf][i]);
        }

    // ---- PV
    bf16x8 pa[2][2], vb[2][4];
#pragma unroll
    for (int mf = 0; mf < 2; ++mf) {
      int rp = mf * 16 + l15;
      pa[0][mf] = *(const bf16x8*)&Pl[wid * 2048 + rp * 64 + (((0 + g) ^ (rp & 7)) << 3)];
      pa[1][mf] = *(const bf16x8*)&Pl[wid * 2048 + rp * 64 + (((4 + g) ^ (rp & 7)) << 3)];
    }
#pragma unroll
    for (int df = 0; df < 4; ++df) {
      int rv = df * 16 + l15;
      vb[0][df] = *(const bf16x8*)&Vt[rv * 64 + (((0 + g) ^ (rv & 7)) << 3)];
      vb[1][df] = *(const bf16x8*)&Vt[rv * 64 + (((4 + g) ^ (rv & 7)) << 3)];
    }
#pragma unroll
    for (int ks = 0; ks < 2; ++ks)
#pragma unroll
      for (int mf = 0; mf < 2; ++mf)
#pragma unroll
        for (int df = 0; df < 4; ++df)
          o[mf][df] = __builtin_amdgcn_mfma_f32_16x16x32_bf16(
              pa[ks][mf], vb[ks][df], o[mf][df], 0, 0, 0);
  }

  // ---- epilogue: Z[b*2048+q][head*64+d] = O / l  (bf16)
#pragma unroll
  for (int mf = 0; mf < 2; ++mf)
#pragma unroll
    for (int df = 0; df < 4; ++df)
#pragma unroll
      for (int i = 0; i < 4; ++i) {
        int q = q0 + wid * 32 + mf * 16 + 4 * g + i;
        int col = head * 64 + df * 16 + l15;
        float v = o[mf][df][i] / lst[mf][i];
        Z[(rowbase + q) * 768 + col] = f2bf(v);
      }
}

// ---------------------------------------------------------------- launch
extern "C" void kernel_launch(void* const* d_in, const int* in_sizes, int n_in,
                              void* d_out, int out_size, void* d_ws, size_t ws_size,
                              hipStream_t stream) {
  const float* x  = (const float*)d_in[0];
  const float* Wq = (const float*)d_in[1];
  const float* Wk = (const float*)d_in[2];
  const float* Wv = (const float*)d_in[3];
  const float* Wo = (const float*)d_in[4];
  const float* bQ = (const float*)d_in[5];
  const float* bK = (const float*)d_in[6];
  const float* bV = (const float*)d_in[7];
  const float* bO = (const float*)d_in[8];
  float* out = (float*)d_out;

  char* ws = (char*)d_ws;
  unsigned short* xb     = (unsigned short*)(ws + 0);          // 12,582,912 B
  unsigned short* wqkv_t = (unsigned short*)(ws + 12582912);   //  3,538,944 B
  unsigned short* wo_t   = (unsigned short*)(ws + 16121856);   //  1,179,648 B
  float*          biasq  = (float*)         (ws + 17301504);   //      9,216 B
  unsigned short* qkv    = (unsigned short*)(ws + 17310720);   // 37,748,736 B
  unsigned short* z      = (unsigned short*)(ws + 55059456);   // 12,582,912 B
  // total: 67,642,368 B

  pack_x<<<6144, 256, 0, stream>>>(x, xb);
  pack_w<<<9225, 256, 0, stream>>>(Wq, Wk, Wv, Wo, bQ, bK, bV, wqkv_t, wo_t, biasq);
  gemm_bt<false><<<dim3(18, 64), 256, 0, stream>>>(xb, wqkv_t, biasq, qkv,
                                                   BATCH * SEQ, 3 * DM, DM);
  attn_fwd<<<dim3(16, NH, BATCH), 256, 0, stream>>>(qkv, z);
  gemm_bt<true><<<dim3(6, 64), 256, 0, stream>>>(z, wo_t, bO, out,
                                                 BATCH * SEQ, DM, DM);
}

// Round 2
// 189.248 us; speedup vs baseline: 1.5912x; 1.5912x over previous
//
#include <hip/hip_runtime.h>
#include <stdint.h>

// Problem constants
#define DM   768
#define NH   12
#define DH   64
#define SEQ  2048
#define BATCH 4
#define LDQKV 2304   // 3*DM

using bf16x8 = __attribute__((ext_vector_type(8))) short;
using f32x4  = __attribute__((ext_vector_type(4))) float;

// 0.125 * log2(e): scores computed in log2 domain -> exp2 softmax
#define QSCALE 0.18033688011112042f

__device__ __forceinline__ unsigned short f2bf(float f) {
  union { float f; unsigned int u; } v; v.f = f;
  unsigned int u = v.u;
  u += 0x7fffu + ((u >> 16) & 1u);           // RNE to bf16
  return (unsigned short)(u >> 16);
}

__device__ __forceinline__ void gload_lds16(const unsigned short* g, unsigned short* l) {
  __builtin_amdgcn_global_load_lds(
      (__attribute__((address_space(1))) void*)g,
      (__attribute__((address_space(3))) void*)l, 16, 0, 0);
}

// ---------------------------------------------------------------- pack_x
__global__ void pack_x(const float* __restrict__ x, unsigned short* __restrict__ xb) {
  int i = (blockIdx.x * 256 + threadIdx.x) * 4;
  float4 v = *(const float4*)(x + i);
  ushort4 o;
  o.x = f2bf(v.x); o.y = f2bf(v.y); o.z = f2bf(v.z); o.w = f2bf(v.w);
  *(ushort4*)(xb + i) = o;
}

// ---------------------------------------------------------------- pack_w
__global__ void pack_w(const float* __restrict__ Wq, const float* __restrict__ Wk,
                       const float* __restrict__ Wv, const float* __restrict__ Wo,
                       const float* __restrict__ bQ, const float* __restrict__ bK,
                       const float* __restrict__ bV,
                       unsigned short* __restrict__ wqkv_t,
                       unsigned short* __restrict__ wo_t,
                       float* __restrict__ biasq) {
  int idx = blockIdx.x * 256 + threadIdx.x;
  const int NW = 2304 * 768;
  const int NO = 768 * 768;
  if (idx < NW) {
    int j = idx / 768, d = idx - j * 768;
    int which = j / 768, nh = j - which * 768;
    const float* W = (which == 0) ? Wq : ((which == 1) ? Wk : Wv);
    float v = W[(nh >> 6) * (768 * 64) + d * 64 + (nh & 63)];
    if (which == 0) v *= QSCALE;
    wqkv_t[idx] = f2bf(v);
  } else if (idx < NW + NO) {
    int k = idx - NW;
    int dcol = k / 768, j = k - dcol * 768;
    wo_t[k] = f2bf(Wo[j * 768 + dcol]);
  } else if (idx < NW + NO + 2304) {
    int j = idx - (NW + NO);
    int which = j / 768, nh = j - which * 768;
    float bv = (which == 0) ? QSCALE * bQ[nh] : ((which == 1) ? bK[nh] : bV[nh]);
    biasq[j] = bv;
  }
}

// ---------------------------------------------------------------- gemm_bt
// (unchanged from round 1 — passed, ~tens of µs; attn is the bottleneck)
template<bool F32OUT>
__global__ __launch_bounds__(256)
void gemm_bt(const unsigned short* __restrict__ A, const unsigned short* __restrict__ Bt,
             const float* __restrict__ bias, void* __restrict__ Cout,
             int M, int N, int K) {
  __shared__ __align__(16) unsigned short As[128 * 64];
  __shared__ __align__(16) unsigned short Bs[128 * 64];
  const int tid = threadIdx.x;
  const int lane = tid & 63, wid = tid >> 6;
  const int l15 = lane & 15, g = lane >> 4;
  const int wr = wid >> 1, wc = wid & 1;
  const int m0 = blockIdx.y * 128, n0 = blockIdx.x * 128;

  const int srow = tid >> 3, sslot = tid & 7;
  const int scol = ((sslot ^ (srow & 7)) << 3);
  const unsigned short* ag = A  + (size_t)(m0 + srow) * K + scol;
  const unsigned short* bg = Bt + (size_t)(n0 + srow) * K + scol;

  f32x4 acc[4][4];
  const f32x4 zz = {0.f, 0.f, 0.f, 0.f};
#pragma unroll
  for (int i = 0; i < 4; ++i)
#pragma unroll
    for (int j = 0; j < 4; ++j) acc[i][j] = zz;

  for (int kt = 0; kt < K; kt += 64) {
#pragma unroll
    for (int p = 0; p < 4; ++p) {
      gload_lds16(ag + (size_t)p * 32 * K + kt, As + p * 2048 + wid * 512);
      gload_lds16(bg + (size_t)p * 32 * K + kt, Bs + p * 2048 + wid * 512);
    }
    __syncthreads();
    bf16x8 af[2][4], bf[2][4];
#pragma unroll
    for (int mf = 0; mf < 4; ++mf) {
      int ra = wr * 64 + mf * 16 + l15;
      int rb = wc * 64 + mf * 16 + l15;
      af[0][mf] = *(const bf16x8*)&As[ra * 64 + (((0 + g) ^ (ra & 7)) << 3)];
      af[1][mf] = *(const bf16x8*)&As[ra * 64 + (((4 + g) ^ (ra & 7)) << 3)];
      bf[0][mf] = *(const bf16x8*)&Bs[rb * 64 + (((0 + g) ^ (rb & 7)) << 3)];
      bf[1][mf] = *(const bf16x8*)&Bs[rb * 64 + (((4 + g) ^ (rb & 7)) << 3)];
    }
#pragma unroll
    for (int ks = 0; ks < 2; ++ks)
#pragma unroll
      for (int mf = 0; mf < 4; ++mf)
#pragma unroll
        for (int nf = 0; nf < 4; ++nf)
          acc[mf][nf] = __builtin_amdgcn_mfma_f32_16x16x32_bf16(
              af[ks][mf], bf[ks][nf], acc[mf][nf], 0, 0, 0);
    __syncthreads();
  }

#pragma unroll
  for (int nf = 0; nf < 4; ++nf) {
    int col = n0 + wc * 64 + nf * 16 + l15;
    float bv = bias[col];
#pragma unroll
    for (int mf = 0; mf < 4; ++mf) {
      int row = m0 + wr * 64 + mf * 16 + g * 4;
#pragma unroll
      for (int i = 0; i < 4; ++i) {
        float v = acc[mf][nf][i] + bv;
        if constexpr (F32OUT)
          ((float*)Cout)[(size_t)(row + i) * N + col] = v;
        else
          ((unsigned short*)Cout)[(size_t)(row + i) * N + col] = f2bf(v);
      }
    }
  }
}

// ---------------------------------------------------------------- attn_fwd
// Triangle-folded flash attention, causal, swapped-QK in-lane softmax.
// Grid (48, 16): bx = head + 12*b, by = p. Block handles q-subtiles p and 31-p
// (64 rows each): waves 0-1 -> subtile p, waves 2-3 -> subtile 31-p.
// K/V double-buffered in LDS; K via global_load_lds (src-swizzled), V via
// reg micro-transpose (loads issued before compute: T14 split).
// QK^T computed as mfma(K, Q): lane holds q = l15, keys = 4g+i per frag ->
// softmax row is lane-local (2 shfl per reduce).
__global__ __launch_bounds__(256, 3)
void attn_fwd(const unsigned short* __restrict__ qkv, unsigned short* __restrict__ Z) {
  __shared__ __align__(16) unsigned short Kl[2][64 * 64];
  __shared__ __align__(16) unsigned short Vt[2][64 * 64];   // [d][key], swizzled
  __shared__ __align__(16) unsigned short Pl[4][32 * 64];   // per-wave [q][key], swizzled

  const int tid = threadIdx.x;
  const int lane = tid & 63, wid = tid >> 6;
  const int l15 = lane & 15, g = lane >> 4;
  const int hb = blockIdx.x;          // 0..47
  const int head = hb % 12, b = hb / 12;
  const int p = blockIdx.y;           // 0..15
  const int qH = 31 - p;
  const int nt = qH + 1;              // KV tiles to process (32-p)
  const int myqt = (wid < 2) ? p : qH;          // my 64-row q-subtile index
  const int qbase = myqt * 64 + (wid & 1) * 32; // my wave's first q row (seq-local)
  const size_t rowbase = (size_t)b * SEQ;

  // Q fragments (QSCALE folded into W_Q): lane holds Q[qbase+mf*16+l15][d]
  bf16x8 qf[2][2]; // [ks][mf]
#pragma unroll
  for (int mf = 0; mf < 2; ++mf) {
    const unsigned short* qrow =
        qkv + (rowbase + qbase + mf * 16 + l15) * LDQKV + head * 64;
    qf[0][mf] = *(const bf16x8*)(qrow + 0  + g * 8);
    qf[1][mf] = *(const bf16x8*)(qrow + 32 + g * 8);
  }

  f32x4 o[2][4];
  const f32x4 zz = {0.f, 0.f, 0.f, 0.f};
#pragma unroll
  for (int mf = 0; mf < 2; ++mf)
#pragma unroll
    for (int df = 0; df < 4; ++df) o[mf][df] = zz;
  float mst[2] = {-1e30f, -1e30f};
  float lst[2] = {0.f, 0.f};

  // K staging (global_load_lds, source-swizzled)
  const int srow = tid >> 3, sslot = tid & 7;
  const int scol = ((sslot ^ (srow & 7)) << 3);
  const unsigned short* kg_ = qkv + (rowbase + srow) * LDQKV + 768 + head * 64 + scol;

  // V micro-transpose mapping
  const int vkg = tid & 15, vdg = tid >> 4;
  const unsigned short* vg_ = qkv + (rowbase + vkg * 4) * LDQKV + 1536 + head * 64 + vdg * 4;

  ushort4 vv[4];
  auto issueK = [&](int kt, int buf) {
    gload_lds16(kg_ + (size_t)(kt * 64) * LDQKV,      &Kl[buf][wid * 512]);
    gload_lds16(kg_ + (size_t)(kt * 64 + 32) * LDQKV, &Kl[buf][2048 + wid * 512]);
  };
  auto loadV = [&](int kt) {
#pragma unroll
    for (int i = 0; i < 4; ++i)
      vv[i] = *(const ushort4*)(vg_ + (size_t)(kt * 64 + i) * LDQKV);
  };
  auto writeV = [&](int buf) {
#pragma unroll
    for (int j = 0; j < 4; ++j) {
      int d = vdg * 4 + j;
      int swz = (vkg >> 1) ^ (d & 7);
      ushort4 w;
      w.x = ((const unsigned short*)&vv[0])[j];
      w.y = ((const unsigned short*)&vv[1])[j];
      w.z = ((const unsigned short*)&vv[2])[j];
      w.w = ((const unsigned short*)&vv[3])[j];
      *(ushort4*)&Vt[buf][d * 64 + swz * 8 + (vkg & 1) * 4] = w;
    }
  };

  // prologue: stage tile 0 into buffer 0
  issueK(0, 0);
  loadV(0);
  writeV(0);
  __syncthreads();

  int cur = 0;
  for (int kv = 0; kv < nt; ++kv) {
    const int nb = cur ^ 1;
    const bool pre = (kv + 1 < nt);
    if (pre) { issueK(kv + 1, nb); loadV(kv + 1); }  // VMEM issued before compute

    if (kv <= myqt) {  // wave-uniform
      // ---- QK^T swapped: s[mf][kf] lane holds q=qbase+mf*16+l15,
      //      keys kv*64 + kf*16 + 4g+i
      bf16x8 kb[2][4];
#pragma unroll
      for (int kf = 0; kf < 4; ++kf) {
        int rk = kf * 16 + l15;
        kb[0][kf] = *(const bf16x8*)&Kl[cur][rk * 64 + (((0 + g) ^ (rk & 7)) << 3)];
        kb[1][kf] = *(const bf16x8*)&Kl[cur][rk * 64 + (((4 + g) ^ (rk & 7)) << 3)];
      }
      f32x4 s[2][4];
#pragma unroll
      for (int mf = 0; mf < 2; ++mf)
#pragma unroll
        for (int kf = 0; kf < 4; ++kf) s[mf][kf] = zz;
#pragma unroll
      for (int ks = 0; ks < 2; ++ks)
#pragma unroll
        for (int mf = 0; mf < 2; ++mf)
#pragma unroll
          for (int kf = 0; kf < 4; ++kf)
            s[mf][kf] = __builtin_amdgcn_mfma_f32_16x16x32_bf16(
                kb[ks][kf], qf[ks][mf], s[mf][kf], 0, 0, 0);

      // causal mask: only the diagonal tile needs it
      if (kv == myqt) {
#pragma unroll
        for (int mf = 0; mf < 2; ++mf) {
          int qgl = qbase + mf * 16 + l15;
#pragma unroll
          for (int kf = 0; kf < 4; ++kf)
#pragma unroll
            for (int i = 0; i < 4; ++i) {
              int kgl = kv * 64 + kf * 16 + 4 * g + i;
              if (kgl > qgl) s[mf][kf][i] = -1e30f;
            }
        }
      }

      // ---- softmax (log2 domain, row fully lane-local up to 4 g-groups)
#pragma unroll
      for (int mf = 0; mf < 2; ++mf) {
        float mx = -1e30f;
#pragma unroll
        for (int kf = 0; kf < 4; ++kf)
#pragma unroll
          for (int i = 0; i < 4; ++i) mx = fmaxf(mx, s[mf][kf][i]);
        mx = fmaxf(mx, __shfl_xor(mx, 16));
        mx = fmaxf(mx, __shfl_xor(mx, 32));
        float mnew = fmaxf(mst[mf], mx);
        float alpha = exp2f(mst[mf] - mnew);
        mst[mf] = mnew;
        float rs = 0.f;
#pragma unroll
        for (int kf = 0; kf < 4; ++kf)
#pragma unroll
          for (int i = 0; i < 4; ++i) {
            float pv = exp2f(s[mf][kf][i] - mnew);
            s[mf][kf][i] = pv;
            rs += pv;
          }
        rs += __shfl_xor(rs, 16);
        rs += __shfl_xor(rs, 32);
        lst[mf] = lst[mf] * alpha + rs;
        // o rows are q=4g+i: gather alpha from lane (4g+i)
        float al[4];
#pragma unroll
        for (int i = 0; i < 4; ++i) al[i] = __shfl(alpha, 4 * g + i);
#pragma unroll
        for (int df = 0; df < 4; ++df)
#pragma unroll
          for (int i = 0; i < 4; ++i) o[mf][df][i] *= al[i];

        // ---- pack P -> Pl[wid] row q_l=mf*16+l15, keys kf*16+4g..+3 (b64 writes)
        int ql = mf * 16 + l15;
#pragma unroll
        for (int kf = 0; kf < 4; ++kf) {
          unsigned int lo = (unsigned int)f2bf(s[mf][kf][0]) |
                            ((unsigned int)f2bf(s[mf][kf][1]) << 16);
          unsigned int hi = (unsigned int)f2bf(s[mf][kf][2]) |
                            ((unsigned int)f2bf(s[mf][kf][3]) << 16);
          int sw = (2 * kf + (g >> 1)) ^ (l15 & 7);
          uint2 w; w.x = lo; w.y = hi;
          *(uint2*)&Pl[wid][ql * 64 + sw * 8 + (g & 1) * 4] = w;
        }
      }

      // ---- PV: pa = A-frag [q][key] read back from Pl
      bf16x8 pa[2][2], vb[2][4];
#pragma unroll
      for (int mf = 0; mf < 2; ++mf) {
#pragma unroll
        for (int ks = 0; ks < 2; ++ks) {
          int sw = (4 * ks + g) ^ (l15 & 7);
          pa[ks][mf] = *(const bf16x8*)&Pl[wid][(mf * 16 + l15) * 64 + sw * 8];
        }
      }
#pragma unroll
      for (int df = 0; df < 4; ++df) {
        int rv = df * 16 + l15;
        vb[0][df] = *(const bf16x8*)&Vt[cur][rv * 64 + (((0 + g) ^ (rv & 7)) << 3)];
        vb[1][df] = *(const bf16x8*)&Vt[cur][rv * 64 + (((4 + g) ^ (rv & 7)) << 3)];
      }
#pragma unroll
      for (int ks = 0; ks < 2; ++ks)
#pragma unroll
        for (int mf = 0; mf < 2; ++mf)
#pragma unroll
          for (int df = 0; df < 4; ++df)
            o[mf][df] = __builtin_amdgcn_mfma_f32_16x16x32_bf16(
                pa[ks][mf], vb[ks][df], o[mf][df], 0, 0, 0);
    }

    if (pre) writeV(nb);   // vmcnt wait happens here, after compute
    __syncthreads();
    cur = nb;
  }

  // ---- epilogue: Z[row][head*64+d] = O / l
#pragma unroll
  for (int mf = 0; mf < 2; ++mf) {
    float rcp[4];
#pragma unroll
    for (int i = 0; i < 4; ++i) {
      float lv = __shfl(lst[mf], 4 * g + i);
      rcp[i] = 1.0f / lv;
    }
#pragma unroll
    for (int df = 0; df < 4; ++df)
#pragma unroll
      for (int i = 0; i < 4; ++i) {
        int q = qbase + mf * 16 + 4 * g + i;
        int col = head * 64 + df * 16 + l15;
        Z[(rowbase + q) * 768 + col] = f2bf(o[mf][df][i] * rcp[i]);
      }
  }
}

// ---------------------------------------------------------------- launch
extern "C" void kernel_launch(void* const* d_in, const int* in_sizes, int n_in,
                              void* d_out, int out_size, void* d_ws, size_t ws_size,
                              hipStream_t stream) {
  const float* x  = (const float*)d_in[0];
  const float* Wq = (const float*)d_in[1];
  const float* Wk = (const float*)d_in[2];
  const float* Wv = (const float*)d_in[3];
  const float* Wo = (const float*)d_in[4];
  const float* bQ = (const float*)d_in[5];
  const float* bK = (const float*)d_in[6];
  const float* bV = (const float*)d_in[7];
  const float* bO = (const float*)d_in[8];
  float* out = (float*)d_out;

  char* ws = (char*)d_ws;
  unsigned short* xb     = (unsigned short*)(ws + 0);          // 12,582,912 B
  unsigned short* wqkv_t = (unsigned short*)(ws + 12582912);   //  3,538,944 B
  unsigned short* wo_t   = (unsigned short*)(ws + 16121856);   //  1,179,648 B
  float*          biasq  = (float*)         (ws + 17301504);   //      9,216 B
  unsigned short* qkv    = (unsigned short*)(ws + 17310720);   // 37,748,736 B
  unsigned short* z      = (unsigned short*)(ws + 55059456);   // 12,582,912 B

  pack_x<<<6144, 256, 0, stream>>>(x, xb);
  pack_w<<<9225, 256, 0, stream>>>(Wq, Wk, Wv, Wo, bQ, bK, bV, wqkv_t, wo_t, biasq);
  gemm_bt<false><<<dim3(18, 64), 256, 0, stream>>>(xb, wqkv_t, biasq, qkv,
                                                   BATCH * SEQ, 3 * DM, DM);
  attn_fwd<<<dim3(48, 16), 256, 0, stream>>>(qkv, z);
  gemm_bt<true><<<dim3(6, 64), 256, 0, stream>>>(z, wo_t, bO, out,
                                                 BATCH * SEQ, DM, DM);
}

// Round 3
// 151.595 us; speedup vs baseline: 1.9865x; 1.2484x over previous
//
#include <hip/hip_runtime.h>
#include <stdint.h>

// Problem constants
#define DM   768
#define NH   12
#define DH   64
#define SEQ  2048
#define BATCH 4
#define LDQKV 2304   // 3*DM

using bf16x8 = __attribute__((ext_vector_type(8))) short;
using f32x4  = __attribute__((ext_vector_type(4))) float;

// 0.125 * log2(e): scores computed in log2 domain -> exp2 softmax
#define QSCALE 0.18033688011112042f

__device__ __forceinline__ unsigned short f2bf(float f) {
  union { float f; unsigned int u; } v; v.f = f;
  unsigned int u = v.u;
  u += 0x7fffu + ((u >> 16) & 1u);           // RNE to bf16
  return (unsigned short)(u >> 16);
}

__device__ __forceinline__ unsigned int cvt_pk_bf16(float a, float b) {
  unsigned int r;
  asm("v_cvt_pk_bf16_f32 %0, %1, %2" : "=v"(r) : "v"(a), "v"(b));
  return r;
}

__device__ __forceinline__ void gload_lds16(const unsigned short* g, unsigned short* l) {
  __builtin_amdgcn_global_load_lds(
      (__attribute__((address_space(1))) void*)g,
      (__attribute__((address_space(3))) void*)l, 16, 0, 0);
}

// ---------------------------------------------------------------- pack_x
__global__ void pack_x(const float* __restrict__ x, unsigned short* __restrict__ xb) {
  int i = (blockIdx.x * 256 + threadIdx.x) * 4;
  float4 v = *(const float4*)(x + i);
  ushort4 o;
  o.x = f2bf(v.x); o.y = f2bf(v.y); o.z = f2bf(v.z); o.w = f2bf(v.w);
  *(ushort4*)(xb + i) = o;
}

// ---------------------------------------------------------------- pack_w
__global__ void pack_w(const float* __restrict__ Wq, const float* __restrict__ Wk,
                       const float* __restrict__ Wv, const float* __restrict__ Wo,
                       const float* __restrict__ bQ, const float* __restrict__ bK,
                       const float* __restrict__ bV,
                       unsigned short* __restrict__ wqkv_t,
                       unsigned short* __restrict__ wo_t,
                       float* __restrict__ biasq) {
  int idx = blockIdx.x * 256 + threadIdx.x;
  const int NW = 2304 * 768;
  const int NO = 768 * 768;
  if (idx < NW) {
    int j = idx / 768, d = idx - j * 768;
    int which = j / 768, nh = j - which * 768;
    const float* W = (which == 0) ? Wq : ((which == 1) ? Wk : Wv);
    float v = W[(nh >> 6) * (768 * 64) + d * 64 + (nh & 63)];
    if (which == 0) v *= QSCALE;
    wqkv_t[idx] = f2bf(v);
  } else if (idx < NW + NO) {
    int k = idx - NW;
    int dcol = k / 768, j = k - dcol * 768;
    wo_t[k] = f2bf(Wo[j * 768 + dcol]);
  } else if (idx < NW + NO + 2304) {
    int j = idx - (NW + NO);
    int which = j / 768, nh = j - which * 768;
    float bv = (which == 0) ? QSCALE * bQ[nh] : ((which == 1) ? bK[nh] : bV[nh]);
    biasq[j] = bv;
  }
}

// ---------------------------------------------------------------- gemm_bt
template<bool F32OUT>
__global__ __launch_bounds__(256)
void gemm_bt(const unsigned short* __restrict__ A, const unsigned short* __restrict__ Bt,
             const float* __restrict__ bias, void* __restrict__ Cout,
             int M, int N, int K) {
  __shared__ __align__(16) unsigned short As[128 * 64];
  __shared__ __align__(16) unsigned short Bs[128 * 64];
  const int tid = threadIdx.x;
  const int lane = tid & 63, wid = tid >> 6;
  const int l15 = lane & 15, g = lane >> 4;
  const int wr = wid >> 1, wc = wid & 1;
  const int m0 = blockIdx.y * 128, n0 = blockIdx.x * 128;

  const int srow = tid >> 3, sslot = tid & 7;
  const int scol = ((sslot ^ (srow & 7)) << 3);
  const unsigned short* ag = A  + (size_t)(m0 + srow) * K + scol;
  const unsigned short* bg = Bt + (size_t)(n0 + srow) * K + scol;

  f32x4 acc[4][4];
  const f32x4 zz = {0.f, 0.f, 0.f, 0.f};
#pragma unroll
  for (int i = 0; i < 4; ++i)
#pragma unroll
    for (int j = 0; j < 4; ++j) acc[i][j] = zz;

  for (int kt = 0; kt < K; kt += 64) {
#pragma unroll
    for (int p = 0; p < 4; ++p) {
      gload_lds16(ag + (size_t)p * 32 * K + kt, As + p * 2048 + wid * 512);
      gload_lds16(bg + (size_t)p * 32 * K + kt, Bs + p * 2048 + wid * 512);
    }
    __syncthreads();
    bf16x8 af[2][4], bf[2][4];
#pragma unroll
    for (int mf = 0; mf < 4; ++mf) {
      int ra = wr * 64 + mf * 16 + l15;
      int rb = wc * 64 + mf * 16 + l15;
      af[0][mf] = *(const bf16x8*)&As[ra * 64 + (((0 + g) ^ (ra & 7)) << 3)];
      af[1][mf] = *(const bf16x8*)&As[ra * 64 + (((4 + g) ^ (ra & 7)) << 3)];
      bf[0][mf] = *(const bf16x8*)&Bs[rb * 64 + (((0 + g) ^ (rb & 7)) << 3)];
      bf[1][mf] = *(const bf16x8*)&Bs[rb * 64 + (((4 + g) ^ (rb & 7)) << 3)];
    }
#pragma unroll
    for (int ks = 0; ks < 2; ++ks)
#pragma unroll
      for (int mf = 0; mf < 4; ++mf)
#pragma unroll
        for (int nf = 0; nf < 4; ++nf)
          acc[mf][nf] = __builtin_amdgcn_mfma_f32_16x16x32_bf16(
              af[ks][mf], bf[ks][nf], acc[mf][nf], 0, 0, 0);
    __syncthreads();
  }

#pragma unroll
  for (int nf = 0; nf < 4; ++nf) {
    int col = n0 + wc * 64 + nf * 16 + l15;
    float bv = bias[col];
#pragma unroll
    for (int mf = 0; mf < 4; ++mf) {
      int row = m0 + wr * 64 + mf * 16 + g * 4;
#pragma unroll
      for (int i = 0; i < 4; ++i) {
        float v = acc[mf][nf][i] + bv;
        if constexpr (F32OUT)
          ((float*)Cout)[(size_t)(row + i) * N + col] = v;
        else
          ((unsigned short*)Cout)[(size_t)(row + i) * N + col] = f2bf(v);
      }
    }
  }
}

// ---------------------------------------------------------------- attn_fwd
// Triangle-folded flash attention, causal, swapped-QK in-lane softmax,
// TRANSPOSED O accumulation: PV computed as mfma(V^T, P) -> O^T[d][q] with
// q at l15 — alpha rescale and 1/l are lane-local (no cross-lane gathers).
// Defer-max (T13, THR=8 in log2 domain). s_setprio around MFMA (T5).
__global__ __launch_bounds__(256, 3)
void attn_fwd(const unsigned short* __restrict__ qkv, unsigned short* __restrict__ Z) {
  __shared__ __align__(16) unsigned short Kl[2][64 * 64];
  __shared__ __align__(16) unsigned short Vt[2][64 * 64];   // [d][key], swizzled
  __shared__ __align__(16) unsigned short Pl[4][32 * 64];   // per-wave [q][key], swizzled

  const int tid = threadIdx.x;
  const int lane = tid & 63, wid = tid >> 6;
  const int l15 = lane & 15, g = lane >> 4;
  const int hb = blockIdx.x;          // 0..47
  const int head = hb % 12, b = hb / 12;
  const int p = blockIdx.y;           // 0..15
  const int qH = 31 - p;
  const int nt = qH + 1;              // KV tiles to process (32-p)
  const int myqt = (wid < 2) ? p : qH;          // my 64-row q-subtile index
  const int qbase = myqt * 64 + (wid & 1) * 32; // my wave's first q row (seq-local)
  const size_t rowbase = (size_t)b * SEQ;

  // Q fragments (QSCALE folded into W_Q): lane holds Q[qbase+mf*16+l15][d]
  bf16x8 qf[2][2]; // [ks][mf]
#pragma unroll
  for (int mf = 0; mf < 2; ++mf) {
    const unsigned short* qrow =
        qkv + (rowbase + qbase + mf * 16 + l15) * LDQKV + head * 64;
    qf[0][mf] = *(const bf16x8*)(qrow + 0  + g * 8);
    qf[1][mf] = *(const bf16x8*)(qrow + 32 + g * 8);
  }

  // O^T accumulator: o[mf][df][i] = O[d = df*16+4g+i][q = qbase+mf*16+l15]
  f32x4 o[2][4];
  const f32x4 zz = {0.f, 0.f, 0.f, 0.f};
#pragma unroll
  for (int mf = 0; mf < 2; ++mf)
#pragma unroll
    for (int df = 0; df < 4; ++df) o[mf][df] = zz;
  float mst[2] = {-1e30f, -1e30f};
  float lst[2] = {0.f, 0.f};

  // K staging (global_load_lds, source-swizzled)
  const int srow = tid >> 3, sslot = tid & 7;
  const int scol = ((sslot ^ (srow & 7)) << 3);
  const unsigned short* kg_ = qkv + (rowbase + srow) * LDQKV + 768 + head * 64 + scol;

  // V micro-transpose mapping
  const int vkg = tid & 15, vdg = tid >> 4;
  const unsigned short* vg_ = qkv + (rowbase + vkg * 4) * LDQKV + 1536 + head * 64 + vdg * 4;

  ushort4 vv[4];
  auto issueK = [&](int kt, int buf) {
    gload_lds16(kg_ + (size_t)(kt * 64) * LDQKV,      &Kl[buf][wid * 512]);
    gload_lds16(kg_ + (size_t)(kt * 64 + 32) * LDQKV, &Kl[buf][2048 + wid * 512]);
  };
  auto loadV = [&](int kt) {
#pragma unroll
    for (int i = 0; i < 4; ++i)
      vv[i] = *(const ushort4*)(vg_ + (size_t)(kt * 64 + i) * LDQKV);
  };
  auto writeV = [&](int buf) {
#pragma unroll
    for (int j = 0; j < 4; ++j) {
      int d = vdg * 4 + j;
      int swz = (vkg >> 1) ^ (d & 7);
      ushort4 w;
      w.x = ((const unsigned short*)&vv[0])[j];
      w.y = ((const unsigned short*)&vv[1])[j];
      w.z = ((const unsigned short*)&vv[2])[j];
      w.w = ((const unsigned short*)&vv[3])[j];
      *(ushort4*)&Vt[buf][d * 64 + swz * 8 + (vkg & 1) * 4] = w;
    }
  };

  // prologue: stage tile 0 into buffer 0
  issueK(0, 0);
  loadV(0);
  writeV(0);
  __syncthreads();

  int cur = 0;
  for (int kv = 0; kv < nt; ++kv) {
    const int nb = cur ^ 1;
    const bool pre = (kv + 1 < nt);
    if (pre) { issueK(kv + 1, nb); loadV(kv + 1); }  // VMEM issued before compute

    if (kv <= myqt) {  // wave-uniform
      // ---- QK^T swapped: s[mf][kf]: q = qbase+mf*16+l15, key = kv*64+kf*16+4g+i
      bf16x8 kb[2][4];
#pragma unroll
      for (int kf = 0; kf < 4; ++kf) {
        int rk = kf * 16 + l15;
        kb[0][kf] = *(const bf16x8*)&Kl[cur][rk * 64 + (((0 + g) ^ (rk & 7)) << 3)];
        kb[1][kf] = *(const bf16x8*)&Kl[cur][rk * 64 + (((4 + g) ^ (rk & 7)) << 3)];
      }
      f32x4 s[2][4];
#pragma unroll
      for (int mf = 0; mf < 2; ++mf)
#pragma unroll
        for (int kf = 0; kf < 4; ++kf) s[mf][kf] = zz;
      __builtin_amdgcn_s_setprio(1);
#pragma unroll
      for (int ks = 0; ks < 2; ++ks)
#pragma unroll
        for (int mf = 0; mf < 2; ++mf)
#pragma unroll
          for (int kf = 0; kf < 4; ++kf)
            s[mf][kf] = __builtin_amdgcn_mfma_f32_16x16x32_bf16(
                kb[ks][kf], qf[ks][mf], s[mf][kf], 0, 0, 0);
      __builtin_amdgcn_s_setprio(0);

      // causal mask: only the diagonal tile needs it
      if (kv == myqt) {
#pragma unroll
        for (int mf = 0; mf < 2; ++mf) {
          int qgl = qbase + mf * 16 + l15;
#pragma unroll
          for (int kf = 0; kf < 4; ++kf)
#pragma unroll
            for (int i = 0; i < 4; ++i) {
              int kgl = kv * 64 + kf * 16 + 4 * g + i;
              if (kgl > qgl) s[mf][kf][i] = -1e30f;
            }
        }
      }

      // ---- softmax (log2 domain; row state lane-local at q=l15)
#pragma unroll
      for (int mf = 0; mf < 2; ++mf) {
        float mx = -1e30f;
#pragma unroll
        for (int kf = 0; kf < 4; ++kf)
#pragma unroll
          for (int i = 0; i < 4; ++i) mx = fmaxf(mx, s[mf][kf][i]);
        mx = fmaxf(mx, __shfl_xor(mx, 16));
        mx = fmaxf(mx, __shfl_xor(mx, 32));
        // defer-max (T13): skip rescale while max growth <= 8 (log2 domain)
        if (!__all(mx <= mst[mf] + 8.0f)) {
          float mnew = fmaxf(mst[mf], mx);
          float alpha = __builtin_amdgcn_exp2f(mst[mf] - mnew);
          mst[mf] = mnew;
          lst[mf] *= alpha;
#pragma unroll
          for (int df = 0; df < 4; ++df)
#pragma unroll
            for (int i = 0; i < 4; ++i) o[mf][df][i] *= alpha;
        }
        float rs = 0.f;
#pragma unroll
        for (int kf = 0; kf < 4; ++kf)
#pragma unroll
          for (int i = 0; i < 4; ++i) {
            float pv = __builtin_amdgcn_exp2f(s[mf][kf][i] - mst[mf]);
            s[mf][kf][i] = pv;
            rs += pv;
          }
        rs += __shfl_xor(rs, 16);
        rs += __shfl_xor(rs, 32);
        lst[mf] += rs;

        // ---- pack P -> Pl[wid]: row q_l = mf*16+l15, keys kf*16+4g..+3
        int ql = mf * 16 + l15;
#pragma unroll
        for (int kf = 0; kf < 4; ++kf) {
          uint2 w;
          w.x = cvt_pk_bf16(s[mf][kf][0], s[mf][kf][1]);
          w.y = cvt_pk_bf16(s[mf][kf][2], s[mf][kf][3]);
          int sw = (2 * kf + (g >> 1)) ^ (l15 & 7);
          *(uint2*)&Pl[wid][ql * 64 + sw * 8 + (g & 1) * 4] = w;
        }
      }

      // ---- PV (transposed): O^T[d][q] += V^T[d][k] * P^T[k][q]
      bf16x8 pa[2][2], vb[2][4];
#pragma unroll
      for (int mf = 0; mf < 2; ++mf) {
#pragma unroll
        for (int ks = 0; ks < 2; ++ks) {
          int sw = (4 * ks + g) ^ (l15 & 7);
          pa[ks][mf] = *(const bf16x8*)&Pl[wid][(mf * 16 + l15) * 64 + sw * 8];
        }
      }
#pragma unroll
      for (int df = 0; df < 4; ++df) {
        int rv = df * 16 + l15;
        vb[0][df] = *(const bf16x8*)&Vt[cur][rv * 64 + (((0 + g) ^ (rv & 7)) << 3)];
        vb[1][df] = *(const bf16x8*)&Vt[cur][rv * 64 + (((4 + g) ^ (rv & 7)) << 3)];
      }
      __builtin_amdgcn_s_setprio(1);
#pragma unroll
      for (int ks = 0; ks < 2; ++ks)
#pragma unroll
        for (int mf = 0; mf < 2; ++mf)
#pragma unroll
          for (int df = 0; df < 4; ++df)
            o[mf][df] = __builtin_amdgcn_mfma_f32_16x16x32_bf16(
                vb[ks][df], pa[ks][mf], o[mf][df], 0, 0, 0);
      __builtin_amdgcn_s_setprio(0);
    }

    if (pre) writeV(nb);   // vmcnt wait happens here, after compute
    __syncthreads();
    cur = nb;
  }

  // ---- epilogue: Z[q][head*64+d] = O^T[d][q] / l   (q = l15: all lane-local)
#pragma unroll
  for (int mf = 0; mf < 2; ++mf) {
    float r = __builtin_amdgcn_rcpf(lst[mf]);
    int q = qbase + mf * 16 + l15;
#pragma unroll
    for (int df = 0; df < 4; ++df) {
      uint2 w;
      w.x = cvt_pk_bf16(o[mf][df][0] * r, o[mf][df][1] * r);
      w.y = cvt_pk_bf16(o[mf][df][2] * r, o[mf][df][3] * r);
      *(uint2*)&Z[(rowbase + q) * 768 + head * 64 + df * 16 + 4 * g] = w;
    }
  }
}

// ---------------------------------------------------------------- launch
extern "C" void kernel_launch(void* const* d_in, const int* in_sizes, int n_in,
                              void* d_out, int out_size, void* d_ws, size_t ws_size,
                              hipStream_t stream) {
  const float* x  = (const float*)d_in[0];
  const float* Wq = (const float*)d_in[1];
  const float* Wk = (const float*)d_in[2];
  const float* Wv = (const float*)d_in[3];
  const float* Wo = (const float*)d_in[4];
  const float* bQ = (const float*)d_in[5];
  const float* bK = (const float*)d_in[6];
  const float* bV = (const float*)d_in[7];
  const float* bO = (const float*)d_in[8];
  float* out = (float*)d_out;

  char* ws = (char*)d_ws;
  unsigned short* xb     = (unsigned short*)(ws + 0);          // 12,582,912 B
  unsigned short* wqkv_t = (unsigned short*)(ws + 12582912);   //  3,538,944 B
  unsigned short* wo_t   = (unsigned short*)(ws + 16121856);   //  1,179,648 B
  float*          biasq  = (float*)         (ws + 17301504);   //      9,216 B
  unsigned short* qkv    = (unsigned short*)(ws + 17310720);   // 37,748,736 B
  unsigned short* z      = (unsigned short*)(ws + 55059456);   // 12,582,912 B

  pack_x<<<6144, 256, 0, stream>>>(x, xb);
  pack_w<<<9225, 256, 0, stream>>>(Wq, Wk, Wv, Wo, bQ, bK, bV, wqkv_t, wo_t, biasq);
  gemm_bt<false><<<dim3(18, 64), 256, 0, stream>>>(xb, wqkv_t, biasq, qkv,
                                                   BATCH * SEQ, 3 * DM, DM);
  attn_fwd<<<dim3(48, 16), 256, 0, stream>>>(qkv, z);
  gemm_bt<true><<<dim3(6, 64), 256, 0, stream>>>(z, wo_t, bO, out,
                                                 BATCH * SEQ, DM, DM);
}

// Round 4
// 151.499 us; speedup vs baseline: 1.9877x; 1.0006x over previous
//
#include <hip/hip_runtime.h>
#include <stdint.h>

// Problem constants
#define DM   768
#define NH   12
#define DH   64
#define SEQ  2048
#define BATCH 4
#define LDQKV 2304   // 3*DM

using bf16x8 = __attribute__((ext_vector_type(8))) short;
using f32x4  = __attribute__((ext_vector_type(4))) float;

// 0.125 * log2(e): scores computed in log2 domain -> exp2 softmax
#define QSCALE 0.18033688011112042f

__device__ __forceinline__ unsigned short f2bf(float f) {
  union { float f; unsigned int u; } v; v.f = f;
  unsigned int u = v.u;
  u += 0x7fffu + ((u >> 16) & 1u);           // RNE to bf16
  return (unsigned short)(u >> 16);
}

__device__ __forceinline__ unsigned int cvt_pk_bf16(float a, float b) {
  unsigned int r;
  asm("v_cvt_pk_bf16_f32 %0, %1, %2" : "=v"(r) : "v"(a), "v"(b));
  return r;
}

__device__ __forceinline__ void gload_lds16(const unsigned short* g, unsigned short* l) {
  __builtin_amdgcn_global_load_lds(
      (__attribute__((address_space(1))) void*)g,
      (__attribute__((address_space(3))) void*)l, 16, 0, 0);
}

// ---------------------------------------------------------------- pack_x
__global__ void pack_x(const float* __restrict__ x, unsigned short* __restrict__ xb) {
  int i = (blockIdx.x * 256 + threadIdx.x) * 4;
  float4 v = *(const float4*)(x + i);
  ushort4 o;
  o.x = f2bf(v.x); o.y = f2bf(v.y); o.z = f2bf(v.z); o.w = f2bf(v.w);
  *(ushort4*)(xb + i) = o;
}

// ---------------------------------------------------------------- pack_w
__global__ void pack_w(const float* __restrict__ Wq, const float* __restrict__ Wk,
                       const float* __restrict__ Wv, const float* __restrict__ Wo,
                       const float* __restrict__ bQ, const float* __restrict__ bK,
                       const float* __restrict__ bV,
                       unsigned short* __restrict__ wqkv_t,
                       unsigned short* __restrict__ wo_t,
                       float* __restrict__ biasq) {
  int idx = blockIdx.x * 256 + threadIdx.x;
  const int NW = 2304 * 768;
  const int NO = 768 * 768;
  if (idx < NW) {
    int j = idx / 768, d = idx - j * 768;
    int which = j / 768, nh = j - which * 768;
    const float* W = (which == 0) ? Wq : ((which == 1) ? Wk : Wv);
    float v = W[(nh >> 6) * (768 * 64) + d * 64 + (nh & 63)];
    if (which == 0) v *= QSCALE;
    wqkv_t[idx] = f2bf(v);
  } else if (idx < NW + NO) {
    int k = idx - NW;
    int dcol = k / 768, j = k - dcol * 768;
    wo_t[k] = f2bf(Wo[j * 768 + dcol]);
  } else if (idx < NW + NO + 2304) {
    int j = idx - (NW + NO);
    int which = j / 768, nh = j - which * 768;
    float bv = (which == 0) ? QSCALE * bQ[nh] : ((which == 1) ? bK[nh] : bV[nh]);
    biasq[j] = bv;
  }
}

// ---------------------------------------------------------------- gemm_bt
// C[M][N] = A[M][K] * Bt[N][K]^T + bias[N].  128xBN tile, BK=64, 4 waves.
// 2-phase pipeline: double-buffered LDS, STAGE(t+1) issued BEFORE compute(t),
// one barrier per K-step (its vmcnt(0) drains the prefetch).
template<int BN, bool F32OUT>
__global__ __launch_bounds__(256)
void gemm_bt(const unsigned short* __restrict__ A, const unsigned short* __restrict__ Bt,
             const float* __restrict__ bias, void* __restrict__ Cout,
             int M, int N, int K) {
  constexpr int NF = BN / 32;   // per-wave col fragments
  __shared__ __align__(16) unsigned short As[2][128 * 64];
  __shared__ __align__(16) unsigned short Bs[2][BN * 64];
  const int tid = threadIdx.x;
  const int lane = tid & 63, wid = tid >> 6;
  const int l15 = lane & 15, g = lane >> 4;
  const int wr = wid >> 1, wc = wid & 1;
  const int m0 = blockIdx.y * 128, n0 = blockIdx.x * BN;

  const int srow = tid >> 3, sslot = tid & 7;
  const int scol = ((sslot ^ (srow & 7)) << 3);
  const unsigned short* ag = A  + (size_t)(m0 + srow) * K + scol;
  const unsigned short* bg = Bt + (size_t)(n0 + srow) * K + scol;

  f32x4 acc[4][NF];
  const f32x4 zz = {0.f, 0.f, 0.f, 0.f};
#pragma unroll
  for (int i = 0; i < 4; ++i)
#pragma unroll
    for (int j = 0; j < NF; ++j) acc[i][j] = zz;

  auto stage = [&](int buf, int kt) {
#pragma unroll
    for (int p = 0; p < 4; ++p)
      gload_lds16(ag + (size_t)(p * 32) * K + kt * 64, &As[buf][p * 2048 + wid * 512]);
#pragma unroll
    for (int p = 0; p < BN / 32; ++p)
      gload_lds16(bg + (size_t)(p * 32) * K + kt * 64, &Bs[buf][p * 2048 + wid * 512]);
  };

  const int nkt = K / 64;
  stage(0, 0);
  __syncthreads();

  int cur = 0;
  for (int t = 0; t < nkt; ++t) {
    if (t + 1 < nkt) stage(cur ^ 1, t + 1);   // prefetch stays in flight over compute
    bf16x8 af[2][4], bf[2][NF];
#pragma unroll
    for (int mf = 0; mf < 4; ++mf) {
      int ra = wr * 64 + mf * 16 + l15;
      af[0][mf] = *(const bf16x8*)&As[cur][ra * 64 + (((0 + g) ^ (ra & 7)) << 3)];
      af[1][mf] = *(const bf16x8*)&As[cur][ra * 64 + (((4 + g) ^ (ra & 7)) << 3)];
    }
#pragma unroll
    for (int nf = 0; nf < NF; ++nf) {
      int rb = wc * (BN / 2) + nf * 16 + l15;
      bf[0][nf] = *(const bf16x8*)&Bs[cur][rb * 64 + (((0 + g) ^ (rb & 7)) << 3)];
      bf[1][nf] = *(const bf16x8*)&Bs[cur][rb * 64 + (((4 + g) ^ (rb & 7)) << 3)];
    }
    __builtin_amdgcn_s_setprio(1);
#pragma unroll
    for (int ks = 0; ks < 2; ++ks)
#pragma unroll
      for (int mf = 0; mf < 4; ++mf)
#pragma unroll
        for (int nf = 0; nf < NF; ++nf)
          acc[mf][nf] = __builtin_amdgcn_mfma_f32_16x16x32_bf16(
              af[ks][mf], bf[ks][nf], acc[mf][nf], 0, 0, 0);
    __builtin_amdgcn_s_setprio(0);
    __syncthreads();   // vmcnt(0)+lgkmcnt(0) drain: prefetch landed, reads done
    cur ^= 1;
  }

#pragma unroll
  for (int nf = 0; nf < NF; ++nf) {
    int col = n0 + wc * (BN / 2) + nf * 16 + l15;
    float bv = bias[col];
#pragma unroll
    for (int mf = 0; mf < 4; ++mf) {
      int row = m0 + wr * 64 + mf * 16 + g * 4;
#pragma unroll
      for (int i = 0; i < 4; ++i) {
        float v = acc[mf][nf][i] + bv;
        if constexpr (F32OUT)
          ((float*)Cout)[(size_t)(row + i) * N + col] = v;
        else
          ((unsigned short*)Cout)[(size_t)(row + i) * N + col] = f2bf(v);
      }
    }
  }
}

// ---------------------------------------------------------------- attn_fwd
// Triangle-folded flash attention, causal, swapped-QK in-lane softmax,
// transposed-O accumulation, defer-max, setprio, and IN-REGISTER P exchange:
// P fragments for PV are built via cvt_pk + v_permlane32_swap + shfl_xor(16)
// (no LDS round-trip; P-LDS buffer removed entirely).
__global__ __launch_bounds__(256, 3)
void attn_fwd(const unsigned short* __restrict__ qkv, unsigned short* __restrict__ Z) {
  __shared__ __align__(16) unsigned short Kl[2][64 * 64];
  __shared__ __align__(16) unsigned short Vt[2][64 * 64];   // [d][key], swizzled

  const int tid = threadIdx.x;
  const int lane = tid & 63, wid = tid >> 6;
  const int l15 = lane & 15, g = lane >> 4;
  const int bsel = g & 1;             // lane bit4
  const int hb = blockIdx.x;          // 0..47
  const int head = hb % 12, b = hb / 12;
  const int p = blockIdx.y;           // 0..15
  const int qH = 31 - p;
  const int nt = qH + 1;              // KV tiles to process (32-p)
  const int myqt = (wid < 2) ? p : qH;          // my 64-row q-subtile index
  const int qbase = myqt * 64 + (wid & 1) * 32; // my wave's first q row (seq-local)
  const size_t rowbase = (size_t)b * SEQ;

  // Q fragments (QSCALE folded into W_Q): lane holds Q[qbase+mf*16+l15][d]
  bf16x8 qf[2][2]; // [ks][mf]
#pragma unroll
  for (int mf = 0; mf < 2; ++mf) {
    const unsigned short* qrow =
        qkv + (rowbase + qbase + mf * 16 + l15) * LDQKV + head * 64;
    qf[0][mf] = *(const bf16x8*)(qrow + 0  + g * 8);
    qf[1][mf] = *(const bf16x8*)(qrow + 32 + g * 8);
  }

  // O^T accumulator: o[mf][df][i] = O[d = df*16+4g+i][q = qbase+mf*16+l15]
  f32x4 o[2][4];
  const f32x4 zz = {0.f, 0.f, 0.f, 0.f};
#pragma unroll
  for (int mf = 0; mf < 2; ++mf)
#pragma unroll
    for (int df = 0; df < 4; ++df) o[mf][df] = zz;
  float mst[2] = {-1e30f, -1e30f};
  float lst[2] = {0.f, 0.f};

  // K staging (global_load_lds, source-swizzled)
  const int srow = tid >> 3, sslot = tid & 7;
  const int scol = ((sslot ^ (srow & 7)) << 3);
  const unsigned short* kg_ = qkv + (rowbase + srow) * LDQKV + 768 + head * 64 + scol;

  // V micro-transpose mapping
  const int vkg = tid & 15, vdg = tid >> 4;
  const unsigned short* vg_ = qkv + (rowbase + vkg * 4) * LDQKV + 1536 + head * 64 + vdg * 4;

  ushort4 vv[4];
  auto issueK = [&](int kt, int buf) {
    gload_lds16(kg_ + (size_t)(kt * 64) * LDQKV,      &Kl[buf][wid * 512]);
    gload_lds16(kg_ + (size_t)(kt * 64 + 32) * LDQKV, &Kl[buf][2048 + wid * 512]);
  };
  auto loadV = [&](int kt) {
#pragma unroll
    for (int i = 0; i < 4; ++i)
      vv[i] = *(const ushort4*)(vg_ + (size_t)(kt * 64 + i) * LDQKV);
  };
  auto writeV = [&](int buf) {
#pragma unroll
    for (int j = 0; j < 4; ++j) {
      int d = vdg * 4 + j;
      int swz = (vkg >> 1) ^ (d & 7);
      ushort4 w;
      w.x = ((const unsigned short*)&vv[0])[j];
      w.y = ((const unsigned short*)&vv[1])[j];
      w.z = ((const unsigned short*)&vv[2])[j];
      w.w = ((const unsigned short*)&vv[3])[j];
      *(ushort4*)&Vt[buf][d * 64 + swz * 8 + (vkg & 1) * 4] = w;
    }
  };

  // prologue: stage tile 0 into buffer 0
  issueK(0, 0);
  loadV(0);
  writeV(0);
  __syncthreads();

  int cur = 0;
  for (int kv = 0; kv < nt; ++kv) {
    const int nb = cur ^ 1;
    const bool pre = (kv + 1 < nt);
    if (pre) { issueK(kv + 1, nb); loadV(kv + 1); }  // VMEM issued before compute

    if (kv <= myqt) {  // wave-uniform
      // ---- QK^T swapped: s[mf][kf]: q = qbase+mf*16+l15, key = kv*64+kf*16+4g+i
      bf16x8 kb[2][4];
#pragma unroll
      for (int kf = 0; kf < 4; ++kf) {
        int rk = kf * 16 + l15;
        kb[0][kf] = *(const bf16x8*)&Kl[cur][rk * 64 + (((0 + g) ^ (rk & 7)) << 3)];
        kb[1][kf] = *(const bf16x8*)&Kl[cur][rk * 64 + (((4 + g) ^ (rk & 7)) << 3)];
      }
      f32x4 s[2][4];
#pragma unroll
      for (int mf = 0; mf < 2; ++mf)
#pragma unroll
        for (int kf = 0; kf < 4; ++kf) s[mf][kf] = zz;
      __builtin_amdgcn_s_setprio(1);
#pragma unroll
      for (int ks = 0; ks < 2; ++ks)
#pragma unroll
        for (int mf = 0; mf < 2; ++mf)
#pragma unroll
          for (int kf = 0; kf < 4; ++kf)
            s[mf][kf] = __builtin_amdgcn_mfma_f32_16x16x32_bf16(
                kb[ks][kf], qf[ks][mf], s[mf][kf], 0, 0, 0);
      __builtin_amdgcn_s_setprio(0);

      // causal mask: only the diagonal tile needs it
      if (kv == myqt) {
#pragma unroll
        for (int mf = 0; mf < 2; ++mf) {
          int qgl = qbase + mf * 16 + l15;
#pragma unroll
          for (int kf = 0; kf < 4; ++kf)
#pragma unroll
            for (int i = 0; i < 4; ++i) {
              int kgl = kv * 64 + kf * 16 + 4 * g + i;
              if (kgl > qgl) s[mf][kf][i] = -1e30f;
            }
        }
      }

      // ---- softmax + in-register P-fragment build
      bf16x8 pa[2][2];   // [ks][mf] B-operand fragments for PV
#pragma unroll
      for (int mf = 0; mf < 2; ++mf) {
        float mx = -1e30f;
#pragma unroll
        for (int kf = 0; kf < 4; ++kf)
#pragma unroll
          for (int i = 0; i < 4; ++i) mx = fmaxf(mx, s[mf][kf][i]);
        mx = fmaxf(mx, __shfl_xor(mx, 16));
        mx = fmaxf(mx, __shfl_xor(mx, 32));
        // defer-max (T13): skip rescale while max growth <= 8 (log2 domain)
        if (!__all(mx <= mst[mf] + 8.0f)) {
          float mnew = fmaxf(mst[mf], mx);
          float alpha = __builtin_amdgcn_exp2f(mst[mf] - mnew);
          mst[mf] = mnew;
          lst[mf] *= alpha;
#pragma unroll
          for (int df = 0; df < 4; ++df)
#pragma unroll
            for (int i = 0; i < 4; ++i) o[mf][df][i] *= alpha;
        }
        float rs = 0.f;
#pragma unroll
        for (int kf = 0; kf < 4; ++kf)
#pragma unroll
          for (int i = 0; i < 4; ++i) {
            float pv = __builtin_amdgcn_exp2f(s[mf][kf][i] - mst[mf]);
            s[mf][kf][i] = pv;
            rs += pv;
          }
        rs += __shfl_xor(rs, 16);
        rs += __shfl_xor(rs, 32);
        lst[mf] += rs;

        // pack P pairs: cc[kf][h] = keys 16kf+4g+2h..+1 (bf16x2)
        unsigned int cc[4][2];
#pragma unroll
        for (int kf = 0; kf < 4; ++kf) {
          cc[kf][0] = cvt_pk_bf16(s[mf][kf][0], s[mf][kf][1]);
          cc[kf][1] = cvt_pk_bf16(s[mf][kf][2], s[mf][kf][3]);
        }
        // exchange: word j (keys 32ks+8g+2j) = cc[2ks+b5][j&1] @ lane(b5'=b4, b4'=j>>1)
#pragma unroll
        for (int ks = 0; ks < 2; ++ks) {
          unsigned int w[4];
#pragma unroll
          for (int h = 0; h < 2; ++h) {
            unsigned int x = cc[2 * ks][h], y = cc[2 * ks + 1][h];
            asm("v_permlane32_swap_b32 %0, %1" : "+v"(x), "+v"(y));
            // x: lane(b5,b4) = cc[2ks+b5][h] @ (half0, b4); y: @ (half1, b4)
            unsigned int sx = (unsigned int)__shfl_xor((int)x, 16);
            unsigned int sy = (unsigned int)__shfl_xor((int)y, 16);
            w[h]     = bsel ? sy : x;    // p=0
            w[2 + h] = bsel ? y  : sx;   // p=1
          }
          union { unsigned int u[4]; bf16x8 v; } pu;
          pu.u[0] = w[0]; pu.u[1] = w[1]; pu.u[2] = w[2]; pu.u[3] = w[3];
          pa[ks][mf] = pu.v;
        }
      }

      // ---- PV (transposed): O^T[d][q] += V^T[d][k] * P^T[k][q]
      bf16x8 vb[2][4];
#pragma unroll
      for (int df = 0; df < 4; ++df) {
        int rv = df * 16 + l15;
        vb[0][df] = *(const bf16x8*)&Vt[cur][rv * 64 + (((0 + g) ^ (rv & 7)) << 3)];
        vb[1][df] = *(const bf16x8*)&Vt[cur][rv * 64 + (((4 + g) ^ (rv & 7)) << 3)];
      }
      __builtin_amdgcn_s_setprio(1);
#pragma unroll
      for (int ks = 0; ks < 2; ++ks)
#pragma unroll
        for (int mf = 0; mf < 2; ++mf)
#pragma unroll
          for (int df = 0; df < 4; ++df)
            o[mf][df] = __builtin_amdgcn_mfma_f32_16x16x32_bf16(
                vb[ks][df], pa[ks][mf], o[mf][df], 0, 0, 0);
      __builtin_amdgcn_s_setprio(0);
    }

    if (pre) writeV(nb);   // vmcnt wait happens here, after compute
    __syncthreads();
    cur = nb;
  }

  // ---- epilogue: Z[q][head*64+d] = O^T[d][q] / l   (q = l15: all lane-local)
#pragma unroll
  for (int mf = 0; mf < 2; ++mf) {
    float r = __builtin_amdgcn_rcpf(lst[mf]);
    int q = qbase + mf * 16 + l15;
#pragma unroll
    for (int df = 0; df < 4; ++df) {
      uint2 w;
      w.x = cvt_pk_bf16(o[mf][df][0] * r, o[mf][df][1] * r);
      w.y = cvt_pk_bf16(o[mf][df][2] * r, o[mf][df][3] * r);
      *(uint2*)&Z[(rowbase + q) * 768 + head * 64 + df * 16 + 4 * g] = w;
    }
  }
}

// ---------------------------------------------------------------- launch
extern "C" void kernel_launch(void* const* d_in, const int* in_sizes, int n_in,
                              void* d_out, int out_size, void* d_ws, size_t ws_size,
                              hipStream_t stream) {
  const float* x  = (const float*)d_in[0];
  const float* Wq = (const float*)d_in[1];
  const float* Wk = (const float*)d_in[2];
  const float* Wv = (const float*)d_in[3];
  const float* Wo = (const float*)d_in[4];
  const float* bQ = (const float*)d_in[5];
  const float* bK = (const float*)d_in[6];
  const float* bV = (const float*)d_in[7];
  const float* bO = (const float*)d_in[8];
  float* out = (float*)d_out;

  char* ws = (char*)d_ws;
  unsigned short* xb     = (unsigned short*)(ws + 0);          // 12,582,912 B
  unsigned short* wqkv_t = (unsigned short*)(ws + 12582912);   //  3,538,944 B
  unsigned short* wo_t   = (unsigned short*)(ws + 16121856);   //  1,179,648 B
  float*          biasq  = (float*)         (ws + 17301504);   //      9,216 B
  unsigned short* qkv    = (unsigned short*)(ws + 17310720);   // 37,748,736 B
  unsigned short* z      = (unsigned short*)(ws + 55059456);   // 12,582,912 B

  pack_x<<<6144, 256, 0, stream>>>(x, xb);
  pack_w<<<9225, 256, 0, stream>>>(Wq, Wk, Wv, Wo, bQ, bK, bV, wqkv_t, wo_t, biasq);
  gemm_bt<128, false><<<dim3(18, 64), 256, 0, stream>>>(xb, wqkv_t, biasq, qkv,
                                                        BATCH * SEQ, 3 * DM, DM);
  attn_fwd<<<dim3(48, 16), 256, 0, stream>>>(qkv, z);
  gemm_bt<64, true><<<dim3(12, 64), 256, 0, stream>>>(z, wo_t, bO, out,
                                                      BATCH * SEQ, DM, DM);
}

// Round 7
// 147.543 us; speedup vs baseline: 2.0410x; 1.0268x over previous
//
#include <hip/hip_runtime.h>
#include <stdint.h>

// Problem constants
#define DM   768
#define NH   12
#define DH   64
#define SEQ  2048
#define BATCH 4
#define LDQKV 2304   // 3*DM

using bf16x8 = __attribute__((ext_vector_type(8))) short;
using f32x4  = __attribute__((ext_vector_type(4))) float;

// 0.125 * log2(e): scores computed in log2 domain -> exp2 softmax
#define QSCALE 0.18033688011112042f

__device__ __forceinline__ unsigned short f2bf(float f) {
  union { float f; unsigned int u; } v; v.f = f;
  unsigned int u = v.u;
  u += 0x7fffu + ((u >> 16) & 1u);           // RNE to bf16
  return (unsigned short)(u >> 16);
}

__device__ __forceinline__ unsigned int cvt_pk_bf16(float a, float b) {
  unsigned int r;
  asm("v_cvt_pk_bf16_f32 %0, %1, %2" : "=v"(r) : "v"(a), "v"(b));
  return r;
}

__device__ __forceinline__ void gload_lds16(const unsigned short* g, unsigned short* l) {
  __builtin_amdgcn_global_load_lds(
      (__attribute__((address_space(1))) void*)g,
      (__attribute__((address_space(3))) void*)l, 16, 0, 0);
}

// ---------------------------------------------------------------- pack_x
__global__ void pack_x(const float* __restrict__ x, unsigned short* __restrict__ xb) {
  int i = (blockIdx.x * 256 + threadIdx.x) * 8;
  float4 a = *(const float4*)(x + i);
  float4 b = *(const float4*)(x + i + 4);
  uint4 o;
  o.x = cvt_pk_bf16(a.x, a.y);
  o.y = cvt_pk_bf16(a.z, a.w);
  o.z = cvt_pk_bf16(b.x, b.y);
  o.w = cvt_pk_bf16(b.z, b.w);
  *(uint4*)(xb + i) = o;
}

// ---------------------------------------------------------------- pack_w
__global__ void pack_w(const float* __restrict__ Wq, const float* __restrict__ Wk,
                       const float* __restrict__ Wv, const float* __restrict__ Wo,
                       const float* __restrict__ bQ, const float* __restrict__ bK,
                       const float* __restrict__ bV,
                       unsigned short* __restrict__ wqkv_t,
                       unsigned short* __restrict__ wo_t,
                       float* __restrict__ biasq) {
  int idx = blockIdx.x * 256 + threadIdx.x;
  const int NW = 2304 * 768;
  const int NO = 768 * 768;
  if (idx < NW) {
    int j = idx / 768, d = idx - j * 768;
    int which = j / 768, nh = j - which * 768;
    const float* W = (which == 0) ? Wq : ((which == 1) ? Wk : Wv);
    float v = W[(nh >> 6) * (768 * 64) + d * 64 + (nh & 63)];
    if (which == 0) v *= QSCALE;
    wqkv_t[idx] = f2bf(v);
  } else if (idx < NW + NO) {
    int k = idx - NW;
    int dcol = k / 768, j = k - dcol * 768;
    wo_t[k] = f2bf(Wo[j * 768 + dcol]);
  } else if (idx < NW + NO + 2304) {
    int j = idx - (NW + NO);
    int which = j / 768, nh = j - which * 768;
    float bv = (which == 0) ? QSCALE * bQ[nh] : ((which == 1) ? bK[nh] : bV[nh]);
    biasq[j] = bv;
  }
}

// ---------------------------------------------------------------- gemm_bt
// C[M][N] = A[M][K]*Bt[N][K]^T + bias[N]. 128xBN tile, BK=32, 4 waves.
// TRIPLE-buffered LDS + counted s_waitcnt vmcnt(LPS): one full stage stays in
// flight across each barrier (T4). Rotation swizzle phys=(sig+(row>>1))&3 on
// 16B slots: linear gload_lds dest, pre-permuted source cols.
// XCD-bijective block remap (grids here are multiples of 8).
template<int BN, bool F32OUT>
__global__ __launch_bounds__(256)
void gemm_bt(const unsigned short* __restrict__ A, const unsigned short* __restrict__ Bt,
             const float* __restrict__ bias, void* __restrict__ Cout,
             int M, int N, int K) {
  constexpr int NF = BN / 32;        // per-wave col fragments
  constexpr int LPS = 2 + BN / 64;   // gload_lds16 per stage
  __shared__ __align__(16) unsigned short As[3][128 * 32];
  __shared__ __align__(16) unsigned short Bs[3][BN * 32];
  const int tid = threadIdx.x;
  const int lane = tid & 63, wid = tid >> 6;
  const int l15 = lane & 15, g = lane >> 4;
  const int wr = wid >> 1, wc = wid & 1;

  // XCD swizzle: contiguous chunk of blocks per XCD
  const int gX = gridDim.x;
  int flat = blockIdx.x + gX * blockIdx.y;
  int nwg = gX * gridDim.y;
  int swz = (flat & 7) * (nwg >> 3) + (flat >> 3);
  const int m0 = (swz / gX) * 128, n0 = (swz % gX) * BN;

  // staging: thread t -> row (t>>2) (+64 per pass), phys slot t&3,
  // source col block sig = (phys - (row>>1)) & 3  (pass-invariant)
  const int sig = ((tid & 3) - ((tid >> 3) & 3)) & 3;
  const unsigned short* ag = A  + (size_t)(m0 + (tid >> 2)) * K + sig * 8;
  const unsigned short* bg = Bt + (size_t)(n0 + (tid >> 2)) * K + sig * 8;

  f32x4 acc[4][NF];
  const f32x4 zz = {0.f, 0.f, 0.f, 0.f};
#pragma unroll
  for (int i = 0; i < 4; ++i)
#pragma unroll
    for (int j = 0; j < NF; ++j) acc[i][j] = zz;

  // one stage pass = 64 rows x 32 cols = 2048 shorts; wave covers 512 shorts
  auto stage = [&](int buf, int kt) {
#pragma unroll
    for (int p = 0; p < 2; ++p)
      gload_lds16(ag + (size_t)(p * 64) * K + kt * 32, &As[buf][p * 2048 + wid * 512]);
#pragma unroll
    for (int p = 0; p < BN / 64; ++p)
      gload_lds16(bg + (size_t)(p * 64) * K + kt * 32, &Bs[buf][p * 2048 + wid * 512]);
  };

  const int nkt = K / 32;
  stage(0, 0);
  stage(1, 1);

  int cur = 0;
  for (int t = 0; t < nkt; ++t) {
    // wait for MY tile-t loads; leave tile-(t+1)'s LPS loads in flight
    __builtin_amdgcn_sched_barrier(0);
    if (t + 1 < nkt) asm volatile("s_waitcnt vmcnt(%0)" :: "n"(LPS) : "memory");
    else             asm volatile("s_waitcnt vmcnt(0)" ::: "memory");
    __builtin_amdgcn_s_barrier();          // all waves' portions landed;
    __builtin_amdgcn_sched_barrier(0);     // and prev-iter reads complete
    if (t + 2 < nkt) stage(cur == 0 ? 2 : cur - 1, t + 2);

    bf16x8 af[4], bf[NF];
#pragma unroll
    for (int mf = 0; mf < 4; ++mf) {
      int ra = wr * 64 + mf * 16 + l15;
      af[mf] = *(const bf16x8*)&As[cur][ra * 32 + (((g + (ra >> 1)) & 3) << 3)];
    }
#pragma unroll
    for (int nf = 0; nf < NF; ++nf) {
      int rb = wc * (BN / 2) + nf * 16 + l15;
      bf[nf] = *(const bf16x8*)&Bs[cur][rb * 32 + (((g + (rb >> 1)) & 3) << 3)];
    }
    __builtin_amdgcn_s_setprio(1);
#pragma unroll
    for (int mf = 0; mf < 4; ++mf)
#pragma unroll
      for (int nf = 0; nf < NF; ++nf)
        acc[mf][nf] = __builtin_amdgcn_mfma_f32_16x16x32_bf16(
            af[mf], bf[nf], acc[mf][nf], 0, 0, 0);
    __builtin_amdgcn_s_setprio(0);
    cur = (cur == 2) ? 0 : cur + 1;
  }

#pragma unroll
  for (int nf = 0; nf < NF; ++nf) {
    int col = n0 + wc * (BN / 2) + nf * 16 + l15;
    float bv = bias[col];
#pragma unroll
    for (int mf = 0; mf < 4; ++mf) {
      int row = m0 + wr * 64 + mf * 16 + g * 4;
#pragma unroll
      for (int i = 0; i < 4; ++i) {
        float v = acc[mf][nf][i] + bv;
        if constexpr (F32OUT)
          ((float*)Cout)[(size_t)(row + i) * N + col] = v;
        else
          ((unsigned short*)Cout)[(size_t)(row + i) * N + col] = f2bf(v);
      }
    }
  }
}

// ---------------------------------------------------------------- attn_fwd
// REVERTED VERBATIM to the round-4-proven version (passed, absmax 3.9e-3):
// triangle-folded, swapped-QK in-lane softmax, transposed-O, defer-max,
// setprio; reductions via shfl_xor(16/32); P exchange via HW-proven
// p32swap + shfl_xor(16) + select. (permlane16_swap is the round-5/6
// suspect and is excluded this round.)
__global__ __launch_bounds__(256, 3)
void attn_fwd(const unsigned short* __restrict__ qkv, unsigned short* __restrict__ Z) {
  __shared__ __align__(16) unsigned short Kl[2][64 * 64];
  __shared__ __align__(16) unsigned short Vt[2][64 * 64];   // [d][key], swizzled

  const int tid = threadIdx.x;
  const int lane = tid & 63, wid = tid >> 6;
  const int l15 = lane & 15, g = lane >> 4;
  const int bsel = g & 1;             // lane bit4
  const int hb = blockIdx.x;          // 0..47
  const int head = hb % 12, b = hb / 12;
  const int p = blockIdx.y;           // 0..15
  const int qH = 31 - p;
  const int nt = qH + 1;              // KV tiles to process (32-p)
  const int myqt = (wid < 2) ? p : qH;          // my 64-row q-subtile index
  const int qbase = myqt * 64 + (wid & 1) * 32; // my wave's first q row (seq-local)
  const size_t rowbase = (size_t)b * SEQ;

  // Q fragments (QSCALE folded into W_Q): lane holds Q[qbase+mf*16+l15][d]
  bf16x8 qf[2][2]; // [ks][mf]
#pragma unroll
  for (int mf = 0; mf < 2; ++mf) {
    const unsigned short* qrow =
        qkv + (rowbase + qbase + mf * 16 + l15) * LDQKV + head * 64;
    qf[0][mf] = *(const bf16x8*)(qrow + 0  + g * 8);
    qf[1][mf] = *(const bf16x8*)(qrow + 32 + g * 8);
  }

  // O^T accumulator: o[mf][df][i] = O[d = df*16+4g+i][q = qbase+mf*16+l15]
  f32x4 o[2][4];
  const f32x4 zz = {0.f, 0.f, 0.f, 0.f};
#pragma unroll
  for (int mf = 0; mf < 2; ++mf)
#pragma unroll
    for (int df = 0; df < 4; ++df) o[mf][df] = zz;
  float mst[2] = {-1e30f, -1e30f};
  float lst[2] = {0.f, 0.f};

  // K staging (global_load_lds, source-swizzled)
  const int srow = tid >> 3, sslot = tid & 7;
  const int scol = ((sslot ^ (srow & 7)) << 3);
  const unsigned short* kg_ = qkv + (rowbase + srow) * LDQKV + 768 + head * 64 + scol;

  // V micro-transpose mapping
  const int vkg = tid & 15, vdg = tid >> 4;
  const unsigned short* vg_ = qkv + (rowbase + vkg * 4) * LDQKV + 1536 + head * 64 + vdg * 4;

  ushort4 vv[4];
  auto issueK = [&](int kt, int buf) {
    gload_lds16(kg_ + (size_t)(kt * 64) * LDQKV,      &Kl[buf][wid * 512]);
    gload_lds16(kg_ + (size_t)(kt * 64 + 32) * LDQKV, &Kl[buf][2048 + wid * 512]);
  };
  auto loadV = [&](int kt) {
#pragma unroll
    for (int i = 0; i < 4; ++i)
      vv[i] = *(const ushort4*)(vg_ + (size_t)(kt * 64 + i) * LDQKV);
  };
  auto writeV = [&](int buf) {
#pragma unroll
    for (int j = 0; j < 4; ++j) {
      int d = vdg * 4 + j;
      int swz = (vkg >> 1) ^ (d & 7);
      ushort4 w;
      w.x = ((const unsigned short*)&vv[0])[j];
      w.y = ((const unsigned short*)&vv[1])[j];
      w.z = ((const unsigned short*)&vv[2])[j];
      w.w = ((const unsigned short*)&vv[3])[j];
      *(ushort4*)&Vt[buf][d * 64 + swz * 8 + (vkg & 1) * 4] = w;
    }
  };

  // prologue: stage tile 0 into buffer 0
  issueK(0, 0);
  loadV(0);
  writeV(0);
  __syncthreads();

  int cur = 0;
  for (int kv = 0; kv < nt; ++kv) {
    const int nb = cur ^ 1;
    const bool pre = (kv + 1 < nt);
    if (pre) { issueK(kv + 1, nb); loadV(kv + 1); }  // VMEM issued before compute

    if (kv <= myqt) {  // wave-uniform
      // ---- QK^T swapped: s[mf][kf]: q = qbase+mf*16+l15, key = kv*64+kf*16+4g+i
      bf16x8 kb[2][4];
#pragma unroll
      for (int kf = 0; kf < 4; ++kf) {
        int rk = kf * 16 + l15;
        kb[0][kf] = *(const bf16x8*)&Kl[cur][rk * 64 + (((0 + g) ^ (rk & 7)) << 3)];
        kb[1][kf] = *(const bf16x8*)&Kl[cur][rk * 64 + (((4 + g) ^ (rk & 7)) << 3)];
      }
      f32x4 s[2][4];
#pragma unroll
      for (int mf = 0; mf < 2; ++mf)
#pragma unroll
        for (int kf = 0; kf < 4; ++kf) s[mf][kf] = zz;
      __builtin_amdgcn_s_setprio(1);
#pragma unroll
      for (int ks = 0; ks < 2; ++ks)
#pragma unroll
        for (int mf = 0; mf < 2; ++mf)
#pragma unroll
          for (int kf = 0; kf < 4; ++kf)
            s[mf][kf] = __builtin_amdgcn_mfma_f32_16x16x32_bf16(
                kb[ks][kf], qf[ks][mf], s[mf][kf], 0, 0, 0);
      __builtin_amdgcn_s_setprio(0);

      // causal mask: only the diagonal tile needs it
      if (kv == myqt) {
#pragma unroll
        for (int mf = 0; mf < 2; ++mf) {
          int qgl = qbase + mf * 16 + l15;
#pragma unroll
          for (int kf = 0; kf < 4; ++kf)
#pragma unroll
            for (int i = 0; i < 4; ++i) {
              int kgl = kv * 64 + kf * 16 + 4 * g + i;
              if (kgl > qgl) s[mf][kf][i] = -1e30f;
            }
        }
      }

      // ---- softmax + in-register P-fragment build
      bf16x8 pa[2][2];   // [ks][mf] B-operand fragments for PV
#pragma unroll
      for (int mf = 0; mf < 2; ++mf) {
        float mx = -1e30f;
#pragma unroll
        for (int kf = 0; kf < 4; ++kf)
#pragma unroll
          for (int i = 0; i < 4; ++i) mx = fmaxf(mx, s[mf][kf][i]);
        mx = fmaxf(mx, __shfl_xor(mx, 16));
        mx = fmaxf(mx, __shfl_xor(mx, 32));
        // defer-max (T13): skip rescale while max growth <= 8 (log2 domain)
        if (!__all(mx <= mst[mf] + 8.0f)) {
          float mnew = fmaxf(mst[mf], mx);
          float alpha = __builtin_amdgcn_exp2f(mst[mf] - mnew);
          mst[mf] = mnew;
          lst[mf] *= alpha;
#pragma unroll
          for (int df = 0; df < 4; ++df)
#pragma unroll
            for (int i = 0; i < 4; ++i) o[mf][df][i] *= alpha;
        }
        float rs = 0.f;
#pragma unroll
        for (int kf = 0; kf < 4; ++kf)
#pragma unroll
          for (int i = 0; i < 4; ++i) {
            float pv = __builtin_amdgcn_exp2f(s[mf][kf][i] - mst[mf]);
            s[mf][kf][i] = pv;
            rs += pv;
          }
        rs += __shfl_xor(rs, 16);
        rs += __shfl_xor(rs, 32);
        lst[mf] += rs;

        // pack P pairs: cc[kf][h] = keys 16kf+4g+2h..+1 (bf16x2)
        unsigned int cc[4][2];
#pragma unroll
        for (int kf = 0; kf < 4; ++kf) {
          cc[kf][0] = cvt_pk_bf16(s[mf][kf][0], s[mf][kf][1]);
          cc[kf][1] = cvt_pk_bf16(s[mf][kf][2], s[mf][kf][3]);
        }
        // exchange: word j (keys 32ks+8g+2j) = cc[2ks+b5][j&1] @ lane(b5'=b4, b4'=j>>1)
#pragma unroll
        for (int ks = 0; ks < 2; ++ks) {
          unsigned int w[4];
#pragma unroll
          for (int h = 0; h < 2; ++h) {
            unsigned int x = cc[2 * ks][h], y = cc[2 * ks + 1][h];
            asm("v_permlane32_swap_b32 %0, %1" : "+v"(x), "+v"(y));
            // x: lane(b5,b4) = cc[2ks+b5][h] @ (half0, b4); y: @ (half1, b4)
            unsigned int sx = (unsigned int)__shfl_xor((int)x, 16);
            unsigned int sy = (unsigned int)__shfl_xor((int)y, 16);
            w[h]     = bsel ? sy : x;    // p=0
            w[2 + h] = bsel ? y  : sx;   // p=1
          }
          union { unsigned int u[4]; bf16x8 v; } pu;
          pu.u[0] = w[0]; pu.u[1] = w[1]; pu.u[2] = w[2]; pu.u[3] = w[3];
          pa[ks][mf] = pu.v;
        }
      }

      // ---- PV (transposed): O^T[d][q] += V^T[d][k] * P^T[k][q]
      bf16x8 vb[2][4];
#pragma unroll
      for (int df = 0; df < 4; ++df) {
        int rv = df * 16 + l15;
        vb[0][df] = *(const bf16x8*)&Vt[cur][rv * 64 + (((0 + g) ^ (rv & 7)) << 3)];
        vb[1][df] = *(const bf16x8*)&Vt[cur][rv * 64 + (((4 + g) ^ (rv & 7)) << 3)];
      }
      __builtin_amdgcn_s_setprio(1);
#pragma unroll
      for (int ks = 0; ks < 2; ++ks)
#pragma unroll
        for (int mf = 0; mf < 2; ++mf)
#pragma unroll
          for (int df = 0; df < 4; ++df)
            o[mf][df] = __builtin_amdgcn_mfma_f32_16x16x32_bf16(
                vb[ks][df], pa[ks][mf], o[mf][df], 0, 0, 0);
      __builtin_amdgcn_s_setprio(0);
    }

    if (pre) writeV(nb);   // vmcnt wait happens here, after compute
    __syncthreads();
    cur = nb;
  }

  // ---- epilogue: Z[q][head*64+d] = O^T[d][q] / l   (q = l15: all lane-local)
#pragma unroll
  for (int mf = 0; mf < 2; ++mf) {
    float r = __builtin_amdgcn_rcpf(lst[mf]);
    int q = qbase + mf * 16 + l15;
#pragma unroll
    for (int df = 0; df < 4; ++df) {
      uint2 w;
      w.x = cvt_pk_bf16(o[mf][df][0] * r, o[mf][df][1] * r);
      w.y = cvt_pk_bf16(o[mf][df][2] * r, o[mf][df][3] * r);
      *(uint2*)&Z[(rowbase + q) * 768 + head * 64 + df * 16 + 4 * g] = w;
    }
  }
}

// ---------------------------------------------------------------- launch
extern "C" void kernel_launch(void* const* d_in, const int* in_sizes, int n_in,
                              void* d_out, int out_size, void* d_ws, size_t ws_size,
                              hipStream_t stream) {
  const float* x  = (const float*)d_in[0];
  const float* Wq = (const float*)d_in[1];
  const float* Wk = (const float*)d_in[2];
  const float* Wv = (const float*)d_in[3];
  const float* Wo = (const float*)d_in[4];
  const float* bQ = (const float*)d_in[5];
  const float* bK = (const float*)d_in[6];
  const float* bV = (const float*)d_in[7];
  const float* bO = (const float*)d_in[8];
  float* out = (float*)d_out;

  char* ws = (char*)d_ws;
  unsigned short* xb     = (unsigned short*)(ws + 0);          // 12,582,912 B
  unsigned short* wqkv_t = (unsigned short*)(ws + 12582912);   //  3,538,944 B
  unsigned short* wo_t   = (unsigned short*)(ws + 16121856);   //  1,179,648 B
  float*          biasq  = (float*)         (ws + 17301504);   //      9,216 B
  unsigned short* qkv    = (unsigned short*)(ws + 17310720);   // 37,748,736 B
  unsigned short* z      = (unsigned short*)(ws + 55059456);   // 12,582,912 B

  pack_x<<<3072, 256, 0, stream>>>(x, xb);
  pack_w<<<9225, 256, 0, stream>>>(Wq, Wk, Wv, Wo, bQ, bK, bV, wqkv_t, wo_t, biasq);
  gemm_bt<128, false><<<dim3(18, 64), 256, 0, stream>>>(xb, wqkv_t, biasq, qkv,
                                                        BATCH * SEQ, 3 * DM, DM);
  attn_fwd<<<dim3(48, 16), 256, 0, stream>>>(qkv, z);
  gemm_bt<64, true><<<dim3(12, 64), 256, 0, stream>>>(z, wo_t, bO, out,
                                                      BATCH * SEQ, DM, DM);
}